// Round 5
// baseline (319.521 us; speedup 1.0000x reference)
//
#include <hip/hip_runtime.h>
#include <hip/hip_bf16.h>

// Problem constants (HyperGCNConv: N=100000, M=50000, K=8, DIN=DOUT=128)
#define NV 100000
#define ME 50000
#define NINC (ME * 8)                     // 400000 incidences
#define NBLK ((NV + 255) / 256)           // 391 scan blocks
constexpr float WMED = 1.0f / 13.0f;      // 1/(2K-3), K=8

// ---------------- K1: Y = X @ W + b (fp32, vector ALU) ----------------
// 128 threads, tile 128x128, thread tile 16 rows x 8 cols (acc = 128 VGPR).
// X transposed in LDS [k][row] stride 132 (conflict-free); W fragments read
// straight from global (same 64 KB for every block -> L1/L2 broadcast).
// Per k per thread: 4 ds_read_b128 + 2 global dwordx4 -> 128 FMAs (VALU-bound).
__global__ __launch_bounds__(128, 2) void k_gemm(const float* __restrict__ X,
                                                 const float* __restrict__ W,
                                                 const float* __restrict__ bias,
                                                 float* __restrict__ Y) {
    __shared__ float sXT[64 * 132];   // [k][row], stride 132, one K-half
    const int t = threadIdx.x;        // 0..127
    const int cg = t & 15;            // cols 8cg..8cg+7
    const int rg = t >> 4;            // 0..7 -> rows 16rg..16rg+15
    const int row0 = blockIdx.x * 128;

    float acc[16][8];
    #pragma unroll
    for (int r = 0; r < 16; ++r)
        #pragma unroll
        for (int c = 0; c < 8; ++c) acc[r][c] = 0.f;

    for (int h = 0; h < 2; ++h) {
        __syncthreads();
        // stage X transposed: 128 rows x 64 k. idx -> row = idx&127 (lane-consecutive
        // rows => conflict-free ds_write_b32), kq = idx>>7.
        #pragma unroll
        for (int i = 0; i < 16; ++i) {
            const int idx = t + i * 128;
            const int row = idx & 127;
            const int kq  = idx >> 7;          // 0..15
            int gr = row0 + row; if (gr > NV - 1) gr = NV - 1;
            const float4 v = *(const float4*)(X + (long)gr * 128 + h * 64 + kq * 4);
            sXT[(kq * 4 + 0) * 132 + row] = v.x;
            sXT[(kq * 4 + 1) * 132 + row] = v.y;
            sXT[(kq * 4 + 2) * 132 + row] = v.z;
            sXT[(kq * 4 + 3) * 132 + row] = v.w;
        }
        __syncthreads();

        const float* Wh = W + (long)h * 64 * 128 + cg * 8;
        #pragma unroll 2
        for (int k = 0; k < 64; ++k) {
            const float4 wa = *(const float4*)(Wh + (long)k * 128);
            const float4 wb = *(const float4*)(Wh + (long)k * 128 + 4);
            const float* xr = sXT + k * 132 + rg * 16;
            const float4 xa = *(const float4*)(xr);
            const float4 xb = *(const float4*)(xr + 4);
            const float4 xc = *(const float4*)(xr + 8);
            const float4 xd = *(const float4*)(xr + 12);
            const float xs[16] = {xa.x, xa.y, xa.z, xa.w, xb.x, xb.y, xb.z, xb.w,
                                  xc.x, xc.y, xc.z, xc.w, xd.x, xd.y, xd.z, xd.w};
            const float ws[8] = {wa.x, wa.y, wa.z, wa.w, wb.x, wb.y, wb.z, wb.w};
            #pragma unroll
            for (int r = 0; r < 16; ++r)
                #pragma unroll
                for (int c = 0; c < 8; ++c)
                    acc[r][c] = fmaf(xs[r], ws[c], acc[r][c]);
        }
    }

    const float4 b0 = *(const float4*)(bias + cg * 8);
    const float4 b1 = *(const float4*)(bias + cg * 8 + 4);
    #pragma unroll
    for (int r = 0; r < 16; ++r) {
        const int gr = row0 + rg * 16 + r;
        if (gr < NV) {
            float4 o0, o1;
            o0.x = acc[r][0] + b0.x; o0.y = acc[r][1] + b0.y;
            o0.z = acc[r][2] + b0.z; o0.w = acc[r][3] + b0.w;
            o1.x = acc[r][4] + b1.x; o1.y = acc[r][5] + b1.y;
            o1.z = acc[r][6] + b1.z; o1.w = acc[r][7] + b1.w;
            *(float4*)(Y + (long)gr * 128 + cg * 8)     = o0;
            *(float4*)(Y + (long)gr * 128 + cg * 8 + 4) = o1;
        }
    }
}

// ---------------- K2: per-hyperedge argmax pair (uvpos only) ----------------
__global__ __launch_bounds__(256) void k_edge(const float* __restrict__ Y,
                                              const int* __restrict__ vertex,
                                              int* __restrict__ uvpos) {
    __shared__ float sF[4][8 * 132];
    const int wid = threadIdx.x >> 6;
    const int lane = threadIdx.x & 63;
    const int m = blockIdx.x * 4 + wid;
    float* F = sF[wid];

    int verts[8];
    #pragma unroll
    for (int p = 0; p < 8; ++p) verts[p] = vertex[m * 8 + p];

    #pragma unroll
    for (int p = 0; p < 8; ++p) {
        const float2 v = *(const float2*)(Y + (long)verts[p] * 128 + lane * 2);
        *(float2*)(F + p * 132 + lane * 2) = v;
    }
    __syncthreads();

    const int k = lane >> 3, l = lane & 7;
    float acc = 0.0f;
    const float4* ra = (const float4*)(F + k * 132);
    const float4* rb = (const float4*)(F + l * 132);
    #pragma unroll
    for (int d4 = 0; d4 < 32; ++d4) {
        const float4 a = ra[d4], b = rb[d4];
        acc = fmaf(a.x, b.x, acc);
        acc = fmaf(a.y, b.y, acc);
        acc = fmaf(a.z, b.z, acc);
        acc = fmaf(a.w, b.w, acc);
    }
    const float sqk = __shfl(acc, k * 9);
    const float sql = __shfl(acc, l * 9);
    float v = sqk + sql - 2.0f * acc;
    int idx = lane;
    #pragma unroll
    for (int off = 32; off >= 1; off >>= 1) {
        const float ov = __shfl_xor(v, off);
        const int oi = __shfl_xor(idx, off);
        if (ov > v || (ov == v && oi < idx)) { v = ov; idx = oi; }
    }
    if (lane == 0) uvpos[m] = idx;
}

// ---------------- K2a: init cnt=0, rowptr[NV]=NINC ----------------
__global__ __launch_bounds__(256) void k_init(int* __restrict__ cnt,
                                              int* __restrict__ rowptr) {
    const int i = blockIdx.x * 256 + threadIdx.x;
    if (i < NV) cnt[i] = 0;
    if (i == 0) rowptr[NV] = NINC;
}

// ---------------- CSR build: histogram ----------------
__global__ __launch_bounds__(256) void k_hist(const int* __restrict__ vertex,
                                              int* __restrict__ cnt) {
    const int j = blockIdx.x * 256 + threadIdx.x;
    if (j < NINC) atomicAdd(cnt + vertex[j], 1);
}

// ---------------- CSR build: scan stage 1 (per-block sums) ----------------
__global__ __launch_bounds__(256) void k_scan1(const int* __restrict__ cnt,
                                               int* __restrict__ bsum) {
    __shared__ int s[256];
    const int t = threadIdx.x;
    const int i = blockIdx.x * 256 + t;
    s[t] = (i < NV) ? cnt[i] : 0;
    __syncthreads();
    #pragma unroll
    for (int off = 128; off >= 1; off >>= 1) {
        if (t < off) s[t] += s[t + off];
        __syncthreads();
    }
    if (t == 0) bsum[blockIdx.x] = s[0];
}

// ---------------- CSR build: scan stage 2 (exclusive scan of block sums) ---
__global__ __launch_bounds__(64) void k_scan2(const int* __restrict__ bsum,
                                              int* __restrict__ boff) {
    const int lane = threadIdx.x;   // single wave
    int running = 0;
    for (int c = 0; c * 64 < NBLK; ++c) {
        const int idx = c * 64 + lane;
        int v = (idx < NBLK) ? bsum[idx] : 0;
        int x = v;
        #pragma unroll
        for (int off = 1; off < 64; off <<= 1) {
            const int n = __shfl_up(x, off);
            if (lane >= off) x += n;
        }
        if (idx < NBLK) boff[idx] = running + x - v;   // exclusive
        running += __shfl(x, 63);
    }
}

// ---------------- CSR build: scan stage 3 (rowptr + fill ptr) ----------------
__global__ __launch_bounds__(256) void k_scan3(const int* __restrict__ cnt,
                                               const int* __restrict__ boff,
                                               int* __restrict__ rowptr,
                                               int* __restrict__ fill) {
    __shared__ int s[256];
    const int t = threadIdx.x;
    const int i = blockIdx.x * 256 + t;
    const int v = (i < NV) ? cnt[i] : 0;
    s[t] = v;
    __syncthreads();
    #pragma unroll
    for (int off = 1; off < 256; off <<= 1) {
        const int add = (t >= off) ? s[t - off] : 0;
        __syncthreads();
        s[t] += add;
        __syncthreads();
    }
    if (i < NV) {
        const int excl = boff[blockIdx.x] + s[t] - v;
        rowptr[i] = excl;
        fill[i] = excl;
    }
}

// ---------------- CSR build: fill entries with (m<<1)|role ----------------
__global__ __launch_bounds__(256) void k_fill(const int* __restrict__ vertex,
                                              const int* __restrict__ uvpos,
                                              int* __restrict__ fill,
                                              int* __restrict__ entries) {
    const int j = blockIdx.x * 256 + threadIdx.x;
    if (j < NINC) {
        const int v = vertex[j];
        const int m = j >> 3, p = j & 7;
        const int idx = uvpos[m];
        const int role = (p == (idx >> 3) || p == (idx & 7)) ? 0 : 1;
        const int slot = atomicAdd(fill + v, 1);
        entries[slot] = (m << 1) | role;
    }
}

// ---------------- K3: exact per-vertex degree (no atomics) ----------------
__global__ __launch_bounds__(256) void k_deg(const int* __restrict__ rowptr,
                                             const int* __restrict__ entries,
                                             float* __restrict__ deg) {
    const int i = blockIdx.x * 256 + threadIdx.x;
    if (i >= NV) return;
    const int start = rowptr[i], end = rowptr[i + 1];
    float d = 1.0f;
    for (int e = start; e < end; ++e)
        d += (entries[e] & 1) ? (2.0f * WMED) : (7.0f * WMED);
    deg[i] = d;
}

// ---------------- K4: per-edge w*S, w*P rows (bf16) ----------------
// lane handles dims (2*lane, 2*lane+1): float2 reads, bfloat162 writes.
__global__ __launch_bounds__(256) void k_sp(const float* __restrict__ Y,
                                            const int* __restrict__ vertex,
                                            const int* __restrict__ uvpos,
                                            const float* __restrict__ deg,
                                            __hip_bfloat162* __restrict__ SP) {
    const int wid = threadIdx.x >> 6;
    const int lane = threadIdx.x & 63;
    const int m = blockIdx.x * 4 + wid;

    const int idx = uvpos[m];
    const int ui = idx >> 3, vi = idx & 7;

    float S0 = 0.f, S1 = 0.f, U0 = 0.f, U1 = 0.f, V0 = 0.f, V1 = 0.f;
    #pragma unroll
    for (int p = 0; p < 8; ++p) {
        const int vp = vertex[m * 8 + p];
        const float di = rsqrtf(deg[vp]);
        const float2 y = *(const float2*)(Y + (long)vp * 128 + lane * 2);
        const float r0 = y.x * di;
        const float r1 = y.y * di;
        S0 += r0; S1 += r1;
        if (p == ui) { U0 = r0; U1 = r1; }
        if (p == vi) { V0 = r0; V1 = r1; }
    }
    __hip_bfloat162 s2, p2;
    s2.x = __float2bfloat16(WMED * S0);
    s2.y = __float2bfloat16(WMED * S1);
    p2.x = __float2bfloat16(WMED * (U0 + V0));
    p2.y = __float2bfloat16(WMED * (U1 + V1));
    SP[(long)(2 * m) * 64 + lane] = s2;        // S row (64 bfloat162 per row)
    SP[(long)(2 * m + 1) * 64 + lane] = p2;    // P row
}

// ---------------- K5: per-vertex gather: one bf16 row per incidence --------
__global__ __launch_bounds__(256) void k_gather(const float* __restrict__ Y,
                                                const float* __restrict__ deg,
                                                const int* __restrict__ rowptr,
                                                const int* __restrict__ entries,
                                                const __hip_bfloat162* __restrict__ SP,
                                                float* __restrict__ out) {
    const int wid = threadIdx.x >> 6;
    const int lane = threadIdx.x & 63;
    const int i = blockIdx.x * 4 + wid;

    const float din = rsqrtf(deg[i]);
    const float2 y = *(const float2*)(Y + (long)i * 128 + lane * 2);
    const float xs0 = y.x * din;
    const float xs1 = y.y * din;

    float a0 = 0.f, a1 = 0.f;
    int nuv = 0;
    const int start = rowptr[i], end = rowptr[i + 1];
    for (int e = start; e < end; ++e) {
        const int t = entries[e];
        nuv += (t & 1) ^ 1;
        const __hip_bfloat162 T = SP[(long)t * 64 + lane];
        a0 += __bfloat162float(T.x);
        a1 += __bfloat162float(T.y);
    }
    const float self = 1.0f - WMED * (float)nuv;
    a0 = fmaf(self, xs0, a0);
    a1 = fmaf(self, xs1, a1);
    float2 o;
    o.x = fmaxf(a0 * din, 0.0f);
    o.y = fmaxf(a1 * din, 0.0f);
    *(float2*)(out + (long)i * 128 + lane * 2) = o;
}

extern "C" void kernel_launch(void* const* d_in, const int* in_sizes, int n_in,
                              void* d_out, int out_size, void* d_ws, size_t ws_size,
                              hipStream_t stream) {
    const float* X      = (const float*)d_in[0];   // [N,128]
    const int*   vertex = (const int*)d_in[1];     // [M*8]
    // d_in[2] = edges (repeat(arange(M),8)) -- unused
    const float* W      = (const float*)d_in[3];   // [128,128]
    const float* bias   = (const float*)d_in[4];   // [128]
    float* out = (float*)d_out;                    // [N,128]

    // workspace: Y[N*128] f32 | SP[2M*128] bf16 | deg[N] | uvpos[M] | cnt[N] |
    //            rowptr[N+1] | fill[N] | bsum[NBLK] | boff[NBLK] | entries[NINC]
    float* Y              = (float*)d_ws;
    __hip_bfloat162* SP   = (__hip_bfloat162*)(Y + (long)NV * 128);
    float* deg            = (float*)((__hip_bfloat16*)SP + (long)2 * ME * 128);
    int*   uvpos          = (int*)(deg + NV);
    int*   cnt            = uvpos + ME;
    int*   rowptr         = cnt + NV;
    int*   fill           = rowptr + NV + 1;
    int*   bsum           = fill + NV;
    int*   boff           = bsum + NBLK;
    int*   entries        = boff + NBLK;

    k_gemm <<<(NV + 127) / 128, 128, 0, stream>>>(X, W, bias, Y);
    k_edge <<<ME / 4, 256, 0, stream>>>(Y, vertex, uvpos);
    k_init <<<NBLK, 256, 0, stream>>>(cnt, rowptr);
    k_hist <<<(NINC + 255) / 256, 256, 0, stream>>>(vertex, cnt);
    k_scan1<<<NBLK, 256, 0, stream>>>(cnt, bsum);
    k_scan2<<<1, 64, 0, stream>>>(bsum, boff);
    k_scan3<<<NBLK, 256, 0, stream>>>(cnt, boff, rowptr, fill);
    k_fill <<<(NINC + 255) / 256, 256, 0, stream>>>(vertex, uvpos, fill, entries);
    k_deg  <<<NBLK, 256, 0, stream>>>(rowptr, entries, deg);
    k_sp   <<<ME / 4, 256, 0, stream>>>(Y, vertex, uvpos, deg, SP);
    k_gather<<<NV / 4, 256, 0, stream>>>(Y, deg, rowptr, entries, SP, out);
}

// Round 6
// 315.141 us; speedup vs baseline: 1.0139x; 1.0139x over previous
//
#include <hip/hip_runtime.h>
#include <hip/hip_bf16.h>

// Problem constants (HyperGCNConv: N=100000, M=50000, K=8, DIN=DOUT=128)
#define NV 100000
#define ME 50000
#define NINC (ME * 8)                     // 400000 incidences
#define NBLK ((NV + 255) / 256)           // 391 scan blocks
constexpr float WMED = 1.0f / 13.0f;      // 1/(2K-3), K=8

// ---------------- K1: Y = X @ W + b (fp32, vector ALU) ----------------
// 256 threads, tile 128x128, thread tile 8x8 (acc=64 VGPR).
// K in quarters of 32: LDS = XT[32][136] + W[32][128] = 33.8 KB -> 4 blocks/CU
// (16 waves/CU). rg=t>>4: X reads are 16-lane same-address broadcast (free);
// cg=t&15: W reads 4-lane broadcast. VALU-bound at 4 waves/SIMD.
__global__ __launch_bounds__(256, 4) void k_gemm(const float* __restrict__ X,
                                                 const float* __restrict__ W,
                                                 const float* __restrict__ bias,
                                                 float* __restrict__ Y) {
    __shared__ float sXT[32 * 136];   // [k][row], stride 136
    __shared__ float sW[32 * 128];    // [k][col]
    const int t = threadIdx.x;
    const int cg = t & 15;            // cols 8cg..8cg+7
    const int rg = t >> 4;            // rows 8rg..8rg+7
    const int row0 = blockIdx.x * 128;

    float acc[8][8];
    #pragma unroll
    for (int r = 0; r < 8; ++r)
        #pragma unroll
        for (int c = 0; c < 8; ++c) acc[r][c] = 0.f;

    for (int q = 0; q < 4; ++q) {
        __syncthreads();
        // stage X transposed: 128 rows x 32 k = 1024 float4, 4/thread.
        #pragma unroll
        for (int i = 0; i < 4; ++i) {
            const int idx = t + i * 256;
            const int row = idx & 127;
            const int kq  = idx >> 7;              // 0..7
            int gr = row0 + row; if (gr > NV - 1) gr = NV - 1;
            const float4 v = *(const float4*)(X + (long)gr * 128 + q * 32 + kq * 4);
            sXT[(kq * 4 + 0) * 136 + row] = v.x;
            sXT[(kq * 4 + 1) * 136 + row] = v.y;
            sXT[(kq * 4 + 2) * 136 + row] = v.z;
            sXT[(kq * 4 + 3) * 136 + row] = v.w;
        }
        // stage W quarter: 32 k x 128 = 1024 float4, 4/thread (direct, coalesced)
        #pragma unroll
        for (int i = 0; i < 4; ++i) {
            const int idx = t + i * 256;
            const int k  = idx >> 5;
            const int cq = idx & 31;
            *(float4*)(sW + k * 128 + cq * 4) =
                *(const float4*)(W + (long)(q * 32 + k) * 128 + cq * 4);
        }
        __syncthreads();

        #pragma unroll 4
        for (int k = 0; k < 32; ++k) {
            const float4 xa = *(const float4*)(sXT + k * 136 + rg * 8);
            const float4 xb = *(const float4*)(sXT + k * 136 + rg * 8 + 4);
            const float4 wa = *(const float4*)(sW + k * 128 + cg * 8);
            const float4 wb = *(const float4*)(sW + k * 128 + cg * 8 + 4);
            const float xs[8] = {xa.x, xa.y, xa.z, xa.w, xb.x, xb.y, xb.z, xb.w};
            const float ws[8] = {wa.x, wa.y, wa.z, wa.w, wb.x, wb.y, wb.z, wb.w};
            #pragma unroll
            for (int r = 0; r < 8; ++r)
                #pragma unroll
                for (int c = 0; c < 8; ++c)
                    acc[r][c] = fmaf(xs[r], ws[c], acc[r][c]);
        }
    }

    const float4 b0 = *(const float4*)(bias + cg * 8);
    const float4 b1 = *(const float4*)(bias + cg * 8 + 4);
    #pragma unroll
    for (int r = 0; r < 8; ++r) {
        const int gr = row0 + rg * 8 + r;
        if (gr < NV) {
            float4 o0, o1;
            o0.x = acc[r][0] + b0.x; o0.y = acc[r][1] + b0.y;
            o0.z = acc[r][2] + b0.z; o0.w = acc[r][3] + b0.w;
            o1.x = acc[r][4] + b1.x; o1.y = acc[r][5] + b1.y;
            o1.z = acc[r][6] + b1.z; o1.w = acc[r][7] + b1.w;
            *(float4*)(Y + (long)gr * 128 + cg * 8)     = o0;
            *(float4*)(Y + (long)gr * 128 + cg * 8 + 4) = o1;
        }
    }
}

// ---------------- K2: per-hyperedge argmax pair (uvpos only) ----------------
__global__ __launch_bounds__(256) void k_edge(const float* __restrict__ Y,
                                              const int* __restrict__ vertex,
                                              int* __restrict__ uvpos) {
    __shared__ float sF[4][8 * 132];
    const int wid = threadIdx.x >> 6;
    const int lane = threadIdx.x & 63;
    const int m = blockIdx.x * 4 + wid;
    float* F = sF[wid];

    int verts[8];
    #pragma unroll
    for (int p = 0; p < 8; ++p) verts[p] = vertex[m * 8 + p];

    #pragma unroll
    for (int p = 0; p < 8; ++p) {
        const float2 v = *(const float2*)(Y + (long)verts[p] * 128 + lane * 2);
        *(float2*)(F + p * 132 + lane * 2) = v;
    }
    __syncthreads();

    const int k = lane >> 3, l = lane & 7;
    float acc = 0.0f;
    const float4* ra = (const float4*)(F + k * 132);
    const float4* rb = (const float4*)(F + l * 132);
    #pragma unroll
    for (int d4 = 0; d4 < 32; ++d4) {
        const float4 a = ra[d4], b = rb[d4];
        acc = fmaf(a.x, b.x, acc);
        acc = fmaf(a.y, b.y, acc);
        acc = fmaf(a.z, b.z, acc);
        acc = fmaf(a.w, b.w, acc);
    }
    const float sqk = __shfl(acc, k * 9);
    const float sql = __shfl(acc, l * 9);
    float v = sqk + sql - 2.0f * acc;
    int idx = lane;
    #pragma unroll
    for (int off = 32; off >= 1; off >>= 1) {
        const float ov = __shfl_xor(v, off);
        const int oi = __shfl_xor(idx, off);
        if (ov > v || (ov == v && oi < idx)) { v = ov; idx = oi; }
    }
    if (lane == 0) uvpos[m] = idx;
}

// ---------------- K2a: init cnt=0, rowptr[NV]=NINC ----------------
__global__ __launch_bounds__(256) void k_init(int* __restrict__ cnt,
                                              int* __restrict__ rowptr) {
    const int i = blockIdx.x * 256 + threadIdx.x;
    if (i < NV) cnt[i] = 0;
    if (i == 0) rowptr[NV] = NINC;
}

// ---------------- CSR build: histogram ----------------
__global__ __launch_bounds__(256) void k_hist(const int* __restrict__ vertex,
                                              int* __restrict__ cnt) {
    const int j = blockIdx.x * 256 + threadIdx.x;
    if (j < NINC) atomicAdd(cnt + vertex[j], 1);
}

// ---------------- CSR build: scan stage 1 (per-block sums) ----------------
__global__ __launch_bounds__(256) void k_scan1(const int* __restrict__ cnt,
                                               int* __restrict__ bsum) {
    __shared__ int s[256];
    const int t = threadIdx.x;
    const int i = blockIdx.x * 256 + t;
    s[t] = (i < NV) ? cnt[i] : 0;
    __syncthreads();
    #pragma unroll
    for (int off = 128; off >= 1; off >>= 1) {
        if (t < off) s[t] += s[t + off];
        __syncthreads();
    }
    if (t == 0) bsum[blockIdx.x] = s[0];
}

// ---------------- CSR build: scan stage 2 (exclusive scan of block sums) ---
__global__ __launch_bounds__(64) void k_scan2(const int* __restrict__ bsum,
                                              int* __restrict__ boff) {
    const int lane = threadIdx.x;   // single wave
    int running = 0;
    for (int c = 0; c * 64 < NBLK; ++c) {
        const int idx = c * 64 + lane;
        int v = (idx < NBLK) ? bsum[idx] : 0;
        int x = v;
        #pragma unroll
        for (int off = 1; off < 64; off <<= 1) {
            const int n = __shfl_up(x, off);
            if (lane >= off) x += n;
        }
        if (idx < NBLK) boff[idx] = running + x - v;   // exclusive
        running += __shfl(x, 63);
    }
}

// ---------------- CSR build: scan stage 3 (rowptr + fill ptr) ----------------
__global__ __launch_bounds__(256) void k_scan3(const int* __restrict__ cnt,
                                               const int* __restrict__ boff,
                                               int* __restrict__ rowptr,
                                               int* __restrict__ fill) {
    __shared__ int s[256];
    const int t = threadIdx.x;
    const int i = blockIdx.x * 256 + t;
    const int v = (i < NV) ? cnt[i] : 0;
    s[t] = v;
    __syncthreads();
    #pragma unroll
    for (int off = 1; off < 256; off <<= 1) {
        const int add = (t >= off) ? s[t - off] : 0;
        __syncthreads();
        s[t] += add;
        __syncthreads();
    }
    if (i < NV) {
        const int excl = boff[blockIdx.x] + s[t] - v;
        rowptr[i] = excl;
        fill[i] = excl;
    }
}

// ---------------- CSR build: fill entries with (m<<1)|role ----------------
__global__ __launch_bounds__(256) void k_fill(const int* __restrict__ vertex,
                                              const int* __restrict__ uvpos,
                                              int* __restrict__ fill,
                                              int* __restrict__ entries) {
    const int j = blockIdx.x * 256 + threadIdx.x;
    if (j < NINC) {
        const int v = vertex[j];
        const int m = j >> 3, p = j & 7;
        const int idx = uvpos[m];
        const int role = (p == (idx >> 3) || p == (idx & 7)) ? 0 : 1;
        const int slot = atomicAdd(fill + v, 1);
        entries[slot] = (m << 1) | role;
    }
}

// ---------------- K3: exact per-vertex degree (no atomics) ----------------
__global__ __launch_bounds__(256) void k_deg(const int* __restrict__ rowptr,
                                             const int* __restrict__ entries,
                                             float* __restrict__ deg) {
    const int i = blockIdx.x * 256 + threadIdx.x;
    if (i >= NV) return;
    const int start = rowptr[i], end = rowptr[i + 1];
    float d = 1.0f;
    for (int e = start; e < end; ++e)
        d += (entries[e] & 1) ? (2.0f * WMED) : (7.0f * WMED);
    deg[i] = d;
}

// ---------------- K4: per-edge w*S, w*P rows (bf16) ----------------
// lane handles dims (2*lane, 2*lane+1): float2 reads, bfloat162 writes.
__global__ __launch_bounds__(256) void k_sp(const float* __restrict__ Y,
                                            const int* __restrict__ vertex,
                                            const int* __restrict__ uvpos,
                                            const float* __restrict__ deg,
                                            __hip_bfloat162* __restrict__ SP) {
    const int wid = threadIdx.x >> 6;
    const int lane = threadIdx.x & 63;
    const int m = blockIdx.x * 4 + wid;

    const int idx = uvpos[m];
    const int ui = idx >> 3, vi = idx & 7;

    float S0 = 0.f, S1 = 0.f, U0 = 0.f, U1 = 0.f, V0 = 0.f, V1 = 0.f;
    #pragma unroll
    for (int p = 0; p < 8; ++p) {
        const int vp = vertex[m * 8 + p];
        const float di = rsqrtf(deg[vp]);
        const float2 y = *(const float2*)(Y + (long)vp * 128 + lane * 2);
        const float r0 = y.x * di;
        const float r1 = y.y * di;
        S0 += r0; S1 += r1;
        if (p == ui) { U0 = r0; U1 = r1; }
        if (p == vi) { V0 = r0; V1 = r1; }
    }
    __hip_bfloat162 s2, p2;
    s2.x = __float2bfloat16(WMED * S0);
    s2.y = __float2bfloat16(WMED * S1);
    p2.x = __float2bfloat16(WMED * (U0 + V0));
    p2.y = __float2bfloat16(WMED * (U1 + V1));
    SP[(long)(2 * m) * 64 + lane] = s2;        // S row (64 bfloat162 per row)
    SP[(long)(2 * m + 1) * 64 + lane] = p2;    // P row
}

// ---------------- K5: per-vertex gather: one bf16 row per incidence --------
__global__ __launch_bounds__(256) void k_gather(const float* __restrict__ Y,
                                                const float* __restrict__ deg,
                                                const int* __restrict__ rowptr,
                                                const int* __restrict__ entries,
                                                const __hip_bfloat162* __restrict__ SP,
                                                float* __restrict__ out) {
    const int wid = threadIdx.x >> 6;
    const int lane = threadIdx.x & 63;
    const int i = blockIdx.x * 4 + wid;

    const float din = rsqrtf(deg[i]);
    const float2 y = *(const float2*)(Y + (long)i * 128 + lane * 2);
    const float xs0 = y.x * din;
    const float xs1 = y.y * din;

    float a0 = 0.f, a1 = 0.f;
    int nuv = 0;
    const int start = rowptr[i], end = rowptr[i + 1];
    for (int e = start; e < end; ++e) {
        const int t = entries[e];
        nuv += (t & 1) ^ 1;
        const __hip_bfloat162 T = SP[(long)t * 64 + lane];
        a0 += __bfloat162float(T.x);
        a1 += __bfloat162float(T.y);
    }
    const float self = 1.0f - WMED * (float)nuv;
    a0 = fmaf(self, xs0, a0);
    a1 = fmaf(self, xs1, a1);
    float2 o;
    o.x = fmaxf(a0 * din, 0.0f);
    o.y = fmaxf(a1 * din, 0.0f);
    *(float2*)(out + (long)i * 128 + lane * 2) = o;
}

extern "C" void kernel_launch(void* const* d_in, const int* in_sizes, int n_in,
                              void* d_out, int out_size, void* d_ws, size_t ws_size,
                              hipStream_t stream) {
    const float* X      = (const float*)d_in[0];   // [N,128]
    const int*   vertex = (const int*)d_in[1];     // [M*8]
    // d_in[2] = edges (repeat(arange(M),8)) -- unused
    const float* W      = (const float*)d_in[3];   // [128,128]
    const float* bias   = (const float*)d_in[4];   // [128]
    float* out = (float*)d_out;                    // [N,128]

    // workspace: Y[N*128] f32 | SP[2M*128] bf16 | deg[N] | uvpos[M] | cnt[N] |
    //            rowptr[N+1] | fill[N] | bsum[NBLK] | boff[NBLK] | entries[NINC]
    float* Y              = (float*)d_ws;
    __hip_bfloat162* SP   = (__hip_bfloat162*)(Y + (long)NV * 128);
    float* deg            = (float*)((__hip_bfloat16*)SP + (long)2 * ME * 128);
    int*   uvpos          = (int*)(deg + NV);
    int*   cnt            = uvpos + ME;
    int*   rowptr         = cnt + NV;
    int*   fill           = rowptr + NV + 1;
    int*   bsum           = fill + NV;
    int*   boff           = bsum + NBLK;
    int*   entries        = boff + NBLK;

    k_gemm <<<(NV + 127) / 128, 256, 0, stream>>>(X, W, bias, Y);
    k_edge <<<ME / 4, 256, 0, stream>>>(Y, vertex, uvpos);
    k_init <<<NBLK, 256, 0, stream>>>(cnt, rowptr);
    k_hist <<<(NINC + 255) / 256, 256, 0, stream>>>(vertex, cnt);
    k_scan1<<<NBLK, 256, 0, stream>>>(cnt, bsum);
    k_scan2<<<1, 64, 0, stream>>>(bsum, boff);
    k_scan3<<<NBLK, 256, 0, stream>>>(cnt, boff, rowptr, fill);
    k_fill <<<(NINC + 255) / 256, 256, 0, stream>>>(vertex, uvpos, fill, entries);
    k_deg  <<<NBLK, 256, 0, stream>>>(rowptr, entries, deg);
    k_sp   <<<ME / 4, 256, 0, stream>>>(Y, vertex, uvpos, deg, SP);
    k_gather<<<NV / 4, 256, 0, stream>>>(Y, deg, rowptr, entries, SP, out);
}

// Round 7
// 313.634 us; speedup vs baseline: 1.0188x; 1.0048x over previous
//
#include <hip/hip_runtime.h>
#include <hip/hip_bf16.h>

// Problem constants (HyperGCNConv: N=100000, M=50000, K=8, DIN=DOUT=128)
#define NV 100000
#define ME 50000
#define NINC (ME * 8)                     // 400000 incidences
#define NBLK ((NV + 255) / 256)           // 391 scan blocks
constexpr float WMED = 1.0f / 13.0f;      // 1/(2K-3), K=8

typedef __attribute__((ext_vector_type(8))) short bf16x8;   // MFMA A/B frag
typedef __attribute__((ext_vector_type(4))) float f32x4;    // MFMA C/D frag

static __device__ inline void cvt_split8(const float4& a, const float4& b,
                                         bf16x8& hi, bf16x8& lo) {
    const float v[8] = {a.x, a.y, a.z, a.w, b.x, b.y, b.z, b.w};
    #pragma unroll
    for (int j = 0; j < 8; ++j) {
        __hip_bfloat16 h = __float2bfloat16(v[j]);
        const float hf = __bfloat162float(h);
        __hip_bfloat16 l = __float2bfloat16(v[j] - hf);
        union { __hip_bfloat16 b; short s; } uh{h}, ul{l};
        hi[j] = uh.s;
        lo[j] = ul.s;
    }
}

// ---------------- K1: Y = X @ W + b via split-bf16 MFMA ----------------
// 3-term split (Xh·Wh + Xh·Wl + Xl·Wh) -> ~1e-5 relative error (argmax-safe).
// W split-staged once to LDS in B-frag layout (frag-contiguous, 2-way alias =
// free); X read from global in A-frag order; no barriers in the K-loop.
// Also emits bf16 copy of Y for k_sp.
__global__ __launch_bounds__(256, 2) void k_gemm(const float* __restrict__ X,
                                                 const float* __restrict__ W,
                                                 const float* __restrict__ bias,
                                                 float* __restrict__ Y,
                                                 __hip_bfloat16* __restrict__ Ybf) {
    __shared__ bf16x8 sWh[2048];   // frag (s*4+q)*128 + c  -> W[32s+8q + j][c]
    __shared__ bf16x8 sWl[2048];
    const int t = threadIdx.x;
    const int wv = t >> 6;         // wave 0..3 -> rows 32wv..32wv+31
    const int L  = t & 63;
    const int m  = L & 15;         // A row sel / B,C col sel
    const int q  = L >> 4;         // k-quad / C row-quad

    // ---- stage W split into LDS (one-time) ----
    for (int idx = t; idx < 128 * 32; idx += 256) {
        const int k  = idx >> 5;            // 0..127
        const int c4 = (idx & 31) * 4;      // col group
        const float4 w = *(const float4*)(W + (long)k * 128 + c4);
        const float wv4[4] = {w.x, w.y, w.z, w.w};
        short* swh = (short*)sWh;
        short* swl = (short*)sWl;
        const int base = (k >> 3) * 1024 + (k & 7);
        #pragma unroll
        for (int j = 0; j < 4; ++j) {
            __hip_bfloat16 h = __float2bfloat16(wv4[j]);
            const float hf = __bfloat162float(h);
            __hip_bfloat16 l = __float2bfloat16(wv4[j] - hf);
            union { __hip_bfloat16 b; short s; } uh{h}, ul{l};
            swh[base + (c4 + j) * 8] = uh.s;
            swl[base + (c4 + j) * 8] = ul.s;
        }
    }
    __syncthreads();

    f32x4 acc[2][8];
    #pragma unroll
    for (int tt = 0; tt < 2; ++tt)
        #pragma unroll
        for (int g = 0; g < 8; ++g)
            acc[tt][g] = (f32x4){0.f, 0.f, 0.f, 0.f};

    const int row_base = blockIdx.x * 128 + wv * 32;
    int r0 = row_base + m;      if (r0 > NV - 1) r0 = NV - 1;
    int r1 = row_base + 16 + m; if (r1 > NV - 1) r1 = NV - 1;
    const int qm = q * 128 + m;   // frag offset within a k-step

    #pragma unroll
    for (int s = 0; s < 4; ++s) {
        const int kb = s * 32 + q * 8;
        const float4 a00 = *(const float4*)(X + (long)r0 * 128 + kb);
        const float4 a01 = *(const float4*)(X + (long)r0 * 128 + kb + 4);
        const float4 a10 = *(const float4*)(X + (long)r1 * 128 + kb);
        const float4 a11 = *(const float4*)(X + (long)r1 * 128 + kb + 4);
        bf16x8 ah0, al0, ah1, al1;
        cvt_split8(a00, a01, ah0, al0);
        cvt_split8(a10, a11, ah1, al1);
        const int fb = s * 512 + qm;
        #pragma unroll
        for (int g = 0; g < 8; ++g) {
            const bf16x8 bh = sWh[fb + g * 16];
            const bf16x8 bl = sWl[fb + g * 16];
            acc[0][g] = __builtin_amdgcn_mfma_f32_16x16x32_bf16(ah0, bh, acc[0][g], 0, 0, 0);
            acc[0][g] = __builtin_amdgcn_mfma_f32_16x16x32_bf16(ah0, bl, acc[0][g], 0, 0, 0);
            acc[0][g] = __builtin_amdgcn_mfma_f32_16x16x32_bf16(al0, bh, acc[0][g], 0, 0, 0);
            acc[1][g] = __builtin_amdgcn_mfma_f32_16x16x32_bf16(ah1, bh, acc[1][g], 0, 0, 0);
            acc[1][g] = __builtin_amdgcn_mfma_f32_16x16x32_bf16(ah1, bl, acc[1][g], 0, 0, 0);
            acc[1][g] = __builtin_amdgcn_mfma_f32_16x16x32_bf16(al1, bh, acc[1][g], 0, 0, 0);
        }
    }

    // epilogue: C layout col=lane&15, row=quad*4+reg
    #pragma unroll
    for (int g = 0; g < 8; ++g) {
        const int col = g * 16 + m;
        const float bc = bias[col];
        #pragma unroll
        for (int tt = 0; tt < 2; ++tt) {
            #pragma unroll
            for (int r = 0; r < 4; ++r) {
                const int row = row_base + tt * 16 + q * 4 + r;
                if (row < NV) {
                    const float v = acc[tt][g][r] + bc;
                    Y[(long)row * 128 + col] = v;
                    Ybf[(long)row * 128 + col] = __float2bfloat16(v);
                }
            }
        }
    }
}

// ---------------- K2: per-hyperedge argmax pair (uvpos only) ----------------
__global__ __launch_bounds__(256) void k_edge(const float* __restrict__ Y,
                                              const int* __restrict__ vertex,
                                              int* __restrict__ uvpos) {
    __shared__ float sF[4][8 * 132];
    const int wid = threadIdx.x >> 6;
    const int lane = threadIdx.x & 63;
    const int m = blockIdx.x * 4 + wid;
    float* F = sF[wid];

    int verts[8];
    #pragma unroll
    for (int p = 0; p < 8; ++p) verts[p] = vertex[m * 8 + p];

    #pragma unroll
    for (int p = 0; p < 8; ++p) {
        const float2 v = *(const float2*)(Y + (long)verts[p] * 128 + lane * 2);
        *(float2*)(F + p * 132 + lane * 2) = v;
    }
    __syncthreads();

    const int k = lane >> 3, l = lane & 7;
    float acc = 0.0f;
    const float4* ra = (const float4*)(F + k * 132);
    const float4* rb = (const float4*)(F + l * 132);
    #pragma unroll
    for (int d4 = 0; d4 < 32; ++d4) {
        const float4 a = ra[d4], b = rb[d4];
        acc = fmaf(a.x, b.x, acc);
        acc = fmaf(a.y, b.y, acc);
        acc = fmaf(a.z, b.z, acc);
        acc = fmaf(a.w, b.w, acc);
    }
    const float sqk = __shfl(acc, k * 9);
    const float sql = __shfl(acc, l * 9);
    float v = sqk + sql - 2.0f * acc;
    int idx = lane;
    #pragma unroll
    for (int off = 32; off >= 1; off >>= 1) {
        const float ov = __shfl_xor(v, off);
        const int oi = __shfl_xor(idx, off);
        if (ov > v || (ov == v && oi < idx)) { v = ov; idx = oi; }
    }
    if (lane == 0) uvpos[m] = idx;
}

// ---------------- K2a: init cnt=0, rowptr[NV]=NINC ----------------
__global__ __launch_bounds__(256) void k_init(int* __restrict__ cnt,
                                              int* __restrict__ rowptr) {
    const int i = blockIdx.x * 256 + threadIdx.x;
    if (i < NV) cnt[i] = 0;
    if (i == 0) rowptr[NV] = NINC;
}

// ---------------- CSR build: histogram ----------------
__global__ __launch_bounds__(256) void k_hist(const int* __restrict__ vertex,
                                              int* __restrict__ cnt) {
    const int j = blockIdx.x * 256 + threadIdx.x;
    if (j < NINC) atomicAdd(cnt + vertex[j], 1);
}

// ---------------- CSR build: scan stage 1 (per-block sums) ----------------
__global__ __launch_bounds__(256) void k_scan1(const int* __restrict__ cnt,
                                               int* __restrict__ bsum) {
    __shared__ int s[256];
    const int t = threadIdx.x;
    const int i = blockIdx.x * 256 + t;
    s[t] = (i < NV) ? cnt[i] : 0;
    __syncthreads();
    #pragma unroll
    for (int off = 128; off >= 1; off >>= 1) {
        if (t < off) s[t] += s[t + off];
        __syncthreads();
    }
    if (t == 0) bsum[blockIdx.x] = s[0];
}

// ---------------- CSR build: scan stage 2 (exclusive scan of block sums) ---
__global__ __launch_bounds__(64) void k_scan2(const int* __restrict__ bsum,
                                              int* __restrict__ boff) {
    const int lane = threadIdx.x;   // single wave
    int running = 0;
    for (int c = 0; c * 64 < NBLK; ++c) {
        const int idx = c * 64 + lane;
        int v = (idx < NBLK) ? bsum[idx] : 0;
        int x = v;
        #pragma unroll
        for (int off = 1; off < 64; off <<= 1) {
            const int n = __shfl_up(x, off);
            if (lane >= off) x += n;
        }
        if (idx < NBLK) boff[idx] = running + x - v;   // exclusive
        running += __shfl(x, 63);
    }
}

// ---------------- CSR build: scan stage 3 (rowptr + fill ptr) ----------------
__global__ __launch_bounds__(256) void k_scan3(const int* __restrict__ cnt,
                                               const int* __restrict__ boff,
                                               int* __restrict__ rowptr,
                                               int* __restrict__ fill) {
    __shared__ int s[256];
    const int t = threadIdx.x;
    const int i = blockIdx.x * 256 + t;
    const int v = (i < NV) ? cnt[i] : 0;
    s[t] = v;
    __syncthreads();
    #pragma unroll
    for (int off = 1; off < 256; off <<= 1) {
        const int add = (t >= off) ? s[t - off] : 0;
        __syncthreads();
        s[t] += add;
        __syncthreads();
    }
    if (i < NV) {
        const int excl = boff[blockIdx.x] + s[t] - v;
        rowptr[i] = excl;
        fill[i] = excl;
    }
}

// ---------------- CSR build: fill entries with (m<<1)|role ----------------
__global__ __launch_bounds__(256) void k_fill(const int* __restrict__ vertex,
                                              const int* __restrict__ uvpos,
                                              int* __restrict__ fill,
                                              int* __restrict__ entries) {
    const int j = blockIdx.x * 256 + threadIdx.x;
    if (j < NINC) {
        const int v = vertex[j];
        const int m = j >> 3, p = j & 7;
        const int idx = uvpos[m];
        const int role = (p == (idx >> 3) || p == (idx & 7)) ? 0 : 1;
        const int slot = atomicAdd(fill + v, 1);
        entries[slot] = (m << 1) | role;
    }
}

// ---------------- K3: exact per-vertex degree (no atomics) ----------------
__global__ __launch_bounds__(256) void k_deg(const int* __restrict__ rowptr,
                                             const int* __restrict__ entries,
                                             float* __restrict__ deg) {
    const int i = blockIdx.x * 256 + threadIdx.x;
    if (i >= NV) return;
    const int start = rowptr[i], end = rowptr[i + 1];
    float d = 1.0f;
    for (int e = start; e < end; ++e)
        d += (entries[e] & 1) ? (2.0f * WMED) : (7.0f * WMED);
    deg[i] = d;
}

// ---------------- K4: per-edge w*S, w*P rows (reads bf16 Y copy) ----------
__global__ __launch_bounds__(256) void k_sp(const __hip_bfloat16* __restrict__ Ybf,
                                            const int* __restrict__ vertex,
                                            const int* __restrict__ uvpos,
                                            const float* __restrict__ deg,
                                            __hip_bfloat162* __restrict__ SP) {
    const int wid = threadIdx.x >> 6;
    const int lane = threadIdx.x & 63;
    const int m = blockIdx.x * 4 + wid;

    const int idx = uvpos[m];
    const int ui = idx >> 3, vi = idx & 7;

    float S0 = 0.f, S1 = 0.f, U0 = 0.f, U1 = 0.f, V0 = 0.f, V1 = 0.f;
    #pragma unroll
    for (int p = 0; p < 8; ++p) {
        const int vp = vertex[m * 8 + p];
        const float di = rsqrtf(deg[vp]);
        const __hip_bfloat162 y2 =
            ((const __hip_bfloat162*)(Ybf + (long)vp * 128))[lane];
        const float r0 = __bfloat162float(y2.x) * di;
        const float r1 = __bfloat162float(y2.y) * di;
        S0 += r0; S1 += r1;
        if (p == ui) { U0 = r0; U1 = r1; }
        if (p == vi) { V0 = r0; V1 = r1; }
    }
    __hip_bfloat162 s2, p2;
    s2.x = __float2bfloat16(WMED * S0);
    s2.y = __float2bfloat16(WMED * S1);
    p2.x = __float2bfloat16(WMED * (U0 + V0));
    p2.y = __float2bfloat16(WMED * (U1 + V1));
    SP[(long)(2 * m) * 64 + lane] = s2;        // S row
    SP[(long)(2 * m + 1) * 64 + lane] = p2;    // P row
}

// ---------------- K5: per-vertex gather: one bf16 row per incidence --------
__global__ __launch_bounds__(256) void k_gather(const float* __restrict__ Y,
                                                const float* __restrict__ deg,
                                                const int* __restrict__ rowptr,
                                                const int* __restrict__ entries,
                                                const __hip_bfloat162* __restrict__ SP,
                                                float* __restrict__ out) {
    const int wid = threadIdx.x >> 6;
    const int lane = threadIdx.x & 63;
    const int i = blockIdx.x * 4 + wid;

    const float din = rsqrtf(deg[i]);
    const float2 y = *(const float2*)(Y + (long)i * 128 + lane * 2);
    const float xs0 = y.x * din;
    const float xs1 = y.y * din;

    float a0 = 0.f, a1 = 0.f;
    int nuv = 0;
    const int start = rowptr[i], end = rowptr[i + 1];
    for (int e = start; e < end; ++e) {
        const int t = entries[e];
        nuv += (t & 1) ^ 1;
        const __hip_bfloat162 T = SP[(long)t * 64 + lane];
        a0 += __bfloat162float(T.x);
        a1 += __bfloat162float(T.y);
    }
    const float self = 1.0f - WMED * (float)nuv;
    a0 = fmaf(self, xs0, a0);
    a1 = fmaf(self, xs1, a1);
    float2 o;
    o.x = fmaxf(a0 * din, 0.0f);
    o.y = fmaxf(a1 * din, 0.0f);
    *(float2*)(out + (long)i * 128 + lane * 2) = o;
}

extern "C" void kernel_launch(void* const* d_in, const int* in_sizes, int n_in,
                              void* d_out, int out_size, void* d_ws, size_t ws_size,
                              hipStream_t stream) {
    const float* X      = (const float*)d_in[0];   // [N,128]
    const int*   vertex = (const int*)d_in[1];     // [M*8]
    // d_in[2] = edges (repeat(arange(M),8)) -- unused
    const float* W      = (const float*)d_in[3];   // [128,128]
    const float* bias   = (const float*)d_in[4];   // [128]
    float* out = (float*)d_out;                    // [N,128]

    // workspace: Y[N*128] f32 | Ybf[N*128] bf16 | SP[2M*128] bf16 | deg[N] |
    //            uvpos[M] | cnt[N] | rowptr[N+1] | fill[N] | bsum | boff | entries
    float* Y              = (float*)d_ws;
    __hip_bfloat16* Ybf   = (__hip_bfloat16*)(Y + (long)NV * 128);
    __hip_bfloat162* SP   = (__hip_bfloat162*)(Ybf + (long)NV * 128);
    float* deg            = (float*)((__hip_bfloat16*)SP + (long)2 * ME * 128);
    int*   uvpos          = (int*)(deg + NV);
    int*   cnt            = uvpos + ME;
    int*   rowptr         = cnt + NV;
    int*   fill           = rowptr + NV + 1;
    int*   bsum           = fill + NV;
    int*   boff           = bsum + NBLK;
    int*   entries        = boff + NBLK;

    k_gemm <<<(NV + 127) / 128, 256, 0, stream>>>(X, W, bias, Y, Ybf);
    k_edge <<<ME / 4, 256, 0, stream>>>(Y, vertex, uvpos);
    k_init <<<NBLK, 256, 0, stream>>>(cnt, rowptr);
    k_hist <<<(NINC + 255) / 256, 256, 0, stream>>>(vertex, cnt);
    k_scan1<<<NBLK, 256, 0, stream>>>(cnt, bsum);
    k_scan2<<<1, 64, 0, stream>>>(bsum, boff);
    k_scan3<<<NBLK, 256, 0, stream>>>(cnt, boff, rowptr, fill);
    k_fill <<<(NINC + 255) / 256, 256, 0, stream>>>(vertex, uvpos, fill, entries);
    k_deg  <<<NBLK, 256, 0, stream>>>(rowptr, entries, deg);
    k_sp   <<<ME / 4, 256, 0, stream>>>(Ybf, vertex, uvpos, deg, SP);
    k_gather<<<NV / 4, 256, 0, stream>>>(Y, deg, rowptr, entries, SP, out);
}

// Round 8
// 313.212 us; speedup vs baseline: 1.0201x; 1.0013x over previous
//
#include <hip/hip_runtime.h>
#include <hip/hip_bf16.h>

// Problem constants (HyperGCNConv: N=100000, M=50000, K=8, DIN=DOUT=128)
#define NV 100000
#define ME 50000
#define NINC (ME * 8)                     // 400000 incidences
#define NBLK ((NV + 255) / 256)           // 391 scan blocks
constexpr float WMED = 1.0f / 13.0f;      // 1/(2K-3), K=8

typedef __attribute__((ext_vector_type(8))) short bf16x8;   // MFMA A/B frag
typedef __attribute__((ext_vector_type(4))) float f32x4;    // MFMA C/D frag

static __device__ inline void cvt_split8(const float4& a, const float4& b,
                                         bf16x8& hi, bf16x8& lo) {
    const float v[8] = {a.x, a.y, a.z, a.w, b.x, b.y, b.z, b.w};
    #pragma unroll
    for (int j = 0; j < 8; ++j) {
        __hip_bfloat16 h = __float2bfloat16(v[j]);
        const float hf = __bfloat162float(h);
        __hip_bfloat16 l = __float2bfloat16(v[j] - hf);
        union { __hip_bfloat16 b; short s; } uh{h}, ul{l};
        hi[j] = uh.s;
        lo[j] = ul.s;
    }
}

// ---------------- K1: Y = X @ W + b via split-bf16 MFMA ----------------
// 3-term split (Xh·Wh + Xh·Wl + Xl·Wh) -> ~1e-5 relative error (argmax-safe).
// B-frag LDS layout: frag index (s*8+g)*64 + lane  => the 64 lanes of a wave
// read 64 consecutive 16B frags (1024 contiguous bytes) -> conflict-free.
// (R7 used s*512+q*128+m: q-stride 2048B = bank offset 0 -> 8-way conflict.)
__global__ __launch_bounds__(256, 2) void k_gemm(const float* __restrict__ X,
                                                 const float* __restrict__ W,
                                                 const float* __restrict__ bias,
                                                 float* __restrict__ Y,
                                                 __hip_bfloat16* __restrict__ Ybf) {
    __shared__ bf16x8 sWh[2048];   // frag (s*8+g)*64 + (q*16+m) -> W[32s+8q+j][16g+m]
    __shared__ bf16x8 sWl[2048];
    const int t = threadIdx.x;
    const int wv = t >> 6;         // wave 0..3 -> rows 32wv..32wv+31
    const int L  = t & 63;
    const int m  = L & 15;         // A row sel / B,C col sel
    const int q  = L >> 4;         // k-quad / C row-quad

    // ---- stage W split into LDS (one-time) ----
    for (int idx = t; idx < 128 * 32; idx += 256) {
        const int k  = idx >> 5;            // 0..127
        const int c4 = (idx & 31) * 4;      // col group
        const float4 w = *(const float4*)(W + (long)k * 128 + c4);
        const float wv4[4] = {w.x, w.y, w.z, w.w};
        short* swh = (short*)sWh;
        short* swl = (short*)sWl;
        const int s = k >> 5, qq = (k >> 3) & 3, j = k & 7;
        #pragma unroll
        for (int j2 = 0; j2 < 4; ++j2) {
            const int c = c4 + j2;
            const int frag = (s * 8 + (c >> 4)) * 64 + qq * 16 + (c & 15);
            __hip_bfloat16 h = __float2bfloat16(wv4[j2]);
            const float hf = __bfloat162float(h);
            __hip_bfloat16 l = __float2bfloat16(wv4[j2] - hf);
            union { __hip_bfloat16 b; short s; } uh{h}, ul{l};
            swh[frag * 8 + j] = uh.s;
            swl[frag * 8 + j] = ul.s;
        }
    }
    __syncthreads();

    f32x4 acc[2][8];
    #pragma unroll
    for (int tt = 0; tt < 2; ++tt)
        #pragma unroll
        for (int g = 0; g < 8; ++g)
            acc[tt][g] = (f32x4){0.f, 0.f, 0.f, 0.f};

    const int row_base = blockIdx.x * 128 + wv * 32;
    int r0 = row_base + m;      if (r0 > NV - 1) r0 = NV - 1;
    int r1 = row_base + 16 + m; if (r1 > NV - 1) r1 = NV - 1;

    #pragma unroll
    for (int s = 0; s < 4; ++s) {
        const int kb = s * 32 + q * 8;
        const float4 a00 = *(const float4*)(X + (long)r0 * 128 + kb);
        const float4 a01 = *(const float4*)(X + (long)r0 * 128 + kb + 4);
        const float4 a10 = *(const float4*)(X + (long)r1 * 128 + kb);
        const float4 a11 = *(const float4*)(X + (long)r1 * 128 + kb + 4);
        bf16x8 ah0, al0, ah1, al1;
        cvt_split8(a00, a01, ah0, al0);
        cvt_split8(a10, a11, ah1, al1);
        #pragma unroll
        for (int g = 0; g < 8; ++g) {
            const bf16x8 bh = sWh[(s * 8 + g) * 64 + L];
            const bf16x8 bl = sWl[(s * 8 + g) * 64 + L];
            acc[0][g] = __builtin_amdgcn_mfma_f32_16x16x32_bf16(ah0, bh, acc[0][g], 0, 0, 0);
            acc[0][g] = __builtin_amdgcn_mfma_f32_16x16x32_bf16(ah0, bl, acc[0][g], 0, 0, 0);
            acc[0][g] = __builtin_amdgcn_mfma_f32_16x16x32_bf16(al0, bh, acc[0][g], 0, 0, 0);
            acc[1][g] = __builtin_amdgcn_mfma_f32_16x16x32_bf16(ah1, bh, acc[1][g], 0, 0, 0);
            acc[1][g] = __builtin_amdgcn_mfma_f32_16x16x32_bf16(ah1, bl, acc[1][g], 0, 0, 0);
            acc[1][g] = __builtin_amdgcn_mfma_f32_16x16x32_bf16(al1, bh, acc[1][g], 0, 0, 0);
        }
    }

    // epilogue: C layout col=lane&15, row=quad*4+reg
    #pragma unroll
    for (int g = 0; g < 8; ++g) {
        const int col = g * 16 + m;
        const float bc = bias[col];
        #pragma unroll
        for (int tt = 0; tt < 2; ++tt) {
            #pragma unroll
            for (int r = 0; r < 4; ++r) {
                const int row = row_base + tt * 16 + q * 4 + r;
                if (row < NV) {
                    const float v = acc[tt][g][r] + bc;
                    Y[(long)row * 128 + col] = v;
                    Ybf[(long)row * 128 + col] = __float2bfloat16(v);
                }
            }
        }
    }
}

// ---------------- K2: per-hyperedge argmax pair (uvpos only) ----------------
__global__ __launch_bounds__(256) void k_edge(const float* __restrict__ Y,
                                              const int* __restrict__ vertex,
                                              int* __restrict__ uvpos) {
    __shared__ float sF[4][8 * 132];
    const int wid = threadIdx.x >> 6;
    const int lane = threadIdx.x & 63;
    const int m = blockIdx.x * 4 + wid;
    float* F = sF[wid];

    int verts[8];
    #pragma unroll
    for (int p = 0; p < 8; ++p) verts[p] = vertex[m * 8 + p];

    #pragma unroll
    for (int p = 0; p < 8; ++p) {
        const float2 v = *(const float2*)(Y + (long)verts[p] * 128 + lane * 2);
        *(float2*)(F + p * 132 + lane * 2) = v;
    }
    __syncthreads();

    const int k = lane >> 3, l = lane & 7;
    float acc = 0.0f;
    const float4* ra = (const float4*)(F + k * 132);
    const float4* rb = (const float4*)(F + l * 132);
    #pragma unroll
    for (int d4 = 0; d4 < 32; ++d4) {
        const float4 a = ra[d4], b = rb[d4];
        acc = fmaf(a.x, b.x, acc);
        acc = fmaf(a.y, b.y, acc);
        acc = fmaf(a.z, b.z, acc);
        acc = fmaf(a.w, b.w, acc);
    }
    const float sqk = __shfl(acc, k * 9);
    const float sql = __shfl(acc, l * 9);
    float v = sqk + sql - 2.0f * acc;
    int idx = lane;
    #pragma unroll
    for (int off = 32; off >= 1; off >>= 1) {
        const float ov = __shfl_xor(v, off);
        const int oi = __shfl_xor(idx, off);
        if (ov > v || (ov == v && oi < idx)) { v = ov; idx = oi; }
    }
    if (lane == 0) uvpos[m] = idx;
}

// ---------------- K2a: init cnt=0, rowptr[NV]=NINC ----------------
__global__ __launch_bounds__(256) void k_init(int* __restrict__ cnt,
                                              int* __restrict__ rowptr) {
    const int i = blockIdx.x * 256 + threadIdx.x;
    if (i < NV) cnt[i] = 0;
    if (i == 0) rowptr[NV] = NINC;
}

// ---------------- CSR build: histogram ----------------
__global__ __launch_bounds__(256) void k_hist(const int* __restrict__ vertex,
                                              int* __restrict__ cnt) {
    const int j = blockIdx.x * 256 + threadIdx.x;
    if (j < NINC) atomicAdd(cnt + vertex[j], 1);
}

// ---------------- CSR build: scan stage 1 (per-block sums) ----------------
__global__ __launch_bounds__(256) void k_scan1(const int* __restrict__ cnt,
                                               int* __restrict__ bsum) {
    __shared__ int s[256];
    const int t = threadIdx.x;
    const int i = blockIdx.x * 256 + t;
    s[t] = (i < NV) ? cnt[i] : 0;
    __syncthreads();
    #pragma unroll
    for (int off = 128; off >= 1; off >>= 1) {
        if (t < off) s[t] += s[t + off];
        __syncthreads();
    }
    if (t == 0) bsum[blockIdx.x] = s[0];
}

// ---------------- CSR build: scan stage 2 (exclusive scan of block sums) ---
__global__ __launch_bounds__(64) void k_scan2(const int* __restrict__ bsum,
                                              int* __restrict__ boff) {
    const int lane = threadIdx.x;   // single wave
    int running = 0;
    for (int c = 0; c * 64 < NBLK; ++c) {
        const int idx = c * 64 + lane;
        int v = (idx < NBLK) ? bsum[idx] : 0;
        int x = v;
        #pragma unroll
        for (int off = 1; off < 64; off <<= 1) {
            const int n = __shfl_up(x, off);
            if (lane >= off) x += n;
        }
        if (idx < NBLK) boff[idx] = running + x - v;   // exclusive
        running += __shfl(x, 63);
    }
}

// ---------------- CSR build: scan stage 3 (rowptr + fill ptr) ----------------
__global__ __launch_bounds__(256) void k_scan3(const int* __restrict__ cnt,
                                               const int* __restrict__ boff,
                                               int* __restrict__ rowptr,
                                               int* __restrict__ fill) {
    __shared__ int s[256];
    const int t = threadIdx.x;
    const int i = blockIdx.x * 256 + t;
    const int v = (i < NV) ? cnt[i] : 0;
    s[t] = v;
    __syncthreads();
    #pragma unroll
    for (int off = 1; off < 256; off <<= 1) {
        const int add = (t >= off) ? s[t - off] : 0;
        __syncthreads();
        s[t] += add;
        __syncthreads();
    }
    if (i < NV) {
        const int excl = boff[blockIdx.x] + s[t] - v;
        rowptr[i] = excl;
        fill[i] = excl;
    }
}

// ---------------- CSR build: fill entries with (m<<1)|role ----------------
__global__ __launch_bounds__(256) void k_fill(const int* __restrict__ vertex,
                                              const int* __restrict__ uvpos,
                                              int* __restrict__ fill,
                                              int* __restrict__ entries) {
    const int j = blockIdx.x * 256 + threadIdx.x;
    if (j < NINC) {
        const int v = vertex[j];
        const int m = j >> 3, p = j & 7;
        const int idx = uvpos[m];
        const int role = (p == (idx >> 3) || p == (idx & 7)) ? 0 : 1;
        const int slot = atomicAdd(fill + v, 1);
        entries[slot] = (m << 1) | role;
    }
}

// ---------------- K3: exact per-vertex degree (no atomics) ----------------
__global__ __launch_bounds__(256) void k_deg(const int* __restrict__ rowptr,
                                             const int* __restrict__ entries,
                                             float* __restrict__ deg) {
    const int i = blockIdx.x * 256 + threadIdx.x;
    if (i >= NV) return;
    const int start = rowptr[i], end = rowptr[i + 1];
    float d = 1.0f;
    for (int e = start; e < end; ++e)
        d += (entries[e] & 1) ? (2.0f * WMED) : (7.0f * WMED);
    deg[i] = d;
}

// ---------------- K4: per-edge w*S, w*P rows (reads bf16 Y copy) ----------
__global__ __launch_bounds__(256) void k_sp(const __hip_bfloat16* __restrict__ Ybf,
                                            const int* __restrict__ vertex,
                                            const int* __restrict__ uvpos,
                                            const float* __restrict__ deg,
                                            __hip_bfloat162* __restrict__ SP) {
    const int wid = threadIdx.x >> 6;
    const int lane = threadIdx.x & 63;
    const int m = blockIdx.x * 4 + wid;

    const int idx = uvpos[m];
    const int ui = idx >> 3, vi = idx & 7;

    float S0 = 0.f, S1 = 0.f, U0 = 0.f, U1 = 0.f, V0 = 0.f, V1 = 0.f;
    #pragma unroll
    for (int p = 0; p < 8; ++p) {
        const int vp = vertex[m * 8 + p];
        const float di = rsqrtf(deg[vp]);
        const __hip_bfloat162 y2 =
            ((const __hip_bfloat162*)(Ybf + (long)vp * 128))[lane];
        const float r0 = __bfloat162float(y2.x) * di;
        const float r1 = __bfloat162float(y2.y) * di;
        S0 += r0; S1 += r1;
        if (p == ui) { U0 = r0; U1 = r1; }
        if (p == vi) { V0 = r0; V1 = r1; }
    }
    __hip_bfloat162 s2, p2;
    s2.x = __float2bfloat16(WMED * S0);
    s2.y = __float2bfloat16(WMED * S1);
    p2.x = __float2bfloat16(WMED * (U0 + V0));
    p2.y = __float2bfloat16(WMED * (U1 + V1));
    SP[(long)(2 * m) * 64 + lane] = s2;        // S row
    SP[(long)(2 * m + 1) * 64 + lane] = p2;    // P row
}

// ---------------- K5: per-vertex gather: one bf16 row per incidence --------
__global__ __launch_bounds__(256) void k_gather(const float* __restrict__ Y,
                                                const float* __restrict__ deg,
                                                const int* __restrict__ rowptr,
                                                const int* __restrict__ entries,
                                                const __hip_bfloat162* __restrict__ SP,
                                                float* __restrict__ out) {
    const int wid = threadIdx.x >> 6;
    const int lane = threadIdx.x & 63;
    const int i = blockIdx.x * 4 + wid;

    const float din = rsqrtf(deg[i]);
    const float2 y = *(const float2*)(Y + (long)i * 128 + lane * 2);
    const float xs0 = y.x * din;
    const float xs1 = y.y * din;

    float a0 = 0.f, a1 = 0.f;
    int nuv = 0;
    const int start = rowptr[i], end = rowptr[i + 1];
    for (int e = start; e < end; ++e) {
        const int t = entries[e];
        nuv += (t & 1) ^ 1;
        const __hip_bfloat162 T = SP[(long)t * 64 + lane];
        a0 += __bfloat162float(T.x);
        a1 += __bfloat162float(T.y);
    }
    const float self = 1.0f - WMED * (float)nuv;
    a0 = fmaf(self, xs0, a0);
    a1 = fmaf(self, xs1, a1);
    float2 o;
    o.x = fmaxf(a0 * din, 0.0f);
    o.y = fmaxf(a1 * din, 0.0f);
    *(float2*)(out + (long)i * 128 + lane * 2) = o;
}

extern "C" void kernel_launch(void* const* d_in, const int* in_sizes, int n_in,
                              void* d_out, int out_size, void* d_ws, size_t ws_size,
                              hipStream_t stream) {
    const float* X      = (const float*)d_in[0];   // [N,128]
    const int*   vertex = (const int*)d_in[1];     // [M*8]
    // d_in[2] = edges (repeat(arange(M),8)) -- unused
    const float* W      = (const float*)d_in[3];   // [128,128]
    const float* bias   = (const float*)d_in[4];   // [128]
    float* out = (float*)d_out;                    // [N,128]

    // workspace: Y[N*128] f32 | Ybf[N*128] bf16 | SP[2M*128] bf16 | deg[N] |
    //            uvpos[M] | cnt[N] | rowptr[N+1] | fill[N] | bsum | boff | entries
    float* Y              = (float*)d_ws;
    __hip_bfloat16* Ybf   = (__hip_bfloat16*)(Y + (long)NV * 128);
    __hip_bfloat162* SP   = (__hip_bfloat162*)(Ybf + (long)NV * 128);
    float* deg            = (float*)((__hip_bfloat16*)SP + (long)2 * ME * 128);
    int*   uvpos          = (int*)(deg + NV);
    int*   cnt            = uvpos + ME;
    int*   rowptr         = cnt + NV;
    int*   fill           = rowptr + NV + 1;
    int*   bsum           = fill + NV;
    int*   boff           = bsum + NBLK;
    int*   entries        = boff + NBLK;

    k_gemm <<<(NV + 127) / 128, 256, 0, stream>>>(X, W, bias, Y, Ybf);
    k_edge <<<ME / 4, 256, 0, stream>>>(Y, vertex, uvpos);
    k_init <<<NBLK, 256, 0, stream>>>(cnt, rowptr);
    k_hist <<<(NINC + 255) / 256, 256, 0, stream>>>(vertex, cnt);
    k_scan1<<<NBLK, 256, 0, stream>>>(cnt, bsum);
    k_scan2<<<1, 64, 0, stream>>>(bsum, boff);
    k_scan3<<<NBLK, 256, 0, stream>>>(cnt, boff, rowptr, fill);
    k_fill <<<(NINC + 255) / 256, 256, 0, stream>>>(vertex, uvpos, fill, entries);
    k_deg  <<<NBLK, 256, 0, stream>>>(rowptr, entries, deg);
    k_sp   <<<ME / 4, 256, 0, stream>>>(Ybf, vertex, uvpos, deg, SP);
    k_gather<<<NV / 4, 256, 0, stream>>>(Y, deg, rowptr, entries, SP, out);
}